// Round 6
// baseline (2348.706 us; speedup 1.0000x reference)
//
#include <hip/hip_runtime.h>

#define DD 128
#define HH 15
#define BSHIFT 9                 // 512 nodes per bucket
#define NBUCK 196                // ceil(100000 / 512)
#define CHUNK 4096               // edges per partA / bucket_count block

// ---------------- bucket histogram (LDS, no global scatter atomics) ----------------

__global__ void bucket_count(const int* __restrict__ col, int* __restrict__ bcount, int E) {
    __shared__ int h[NBUCK];
    int tid = threadIdx.x;
    for (int i = tid; i < NBUCK; i += 256) h[i] = 0;
    __syncthreads();
    int start = blockIdx.x * CHUNK;
    for (int k = 0; k < 16; ++k) {
        int e = start + k * 256 + tid;
        if (e < E) atomicAdd(&h[col[e] >> BSHIFT], 1);   // LDS atomic
    }
    __syncthreads();
    for (int i = tid; i < NBUCK; i += 256)
        if (h[i]) atomicAdd(&bcount[i], h[i]);           // ~196 global adds/block
}

// scan 196 bucket counts -> bbase[197] and partA cursors gcur[196]
__global__ void scan196(const int* __restrict__ bcount, int* __restrict__ bbase,
                        int* __restrict__ gcur, int E) {
    __shared__ int sh[256];
    int t = threadIdx.x;
    int v = (t < NBUCK) ? bcount[t] : 0;
    sh[t] = v;
    __syncthreads();
    for (int off = 1; off < 256; off <<= 1) {
        int x = (t >= off) ? sh[t - off] : 0;
        __syncthreads();
        sh[t] += x;
        __syncthreads();
    }
    if (t < NBUCK) { int ex = sh[t] - v; bbase[t] = ex; gcur[t] = ex; }
    if (t == 0) bbase[NBUCK] = E;
}

// ---------------- CSR-lite build: LDS-staged bucket binning into tmp ----------------
// pack = row (17b) | local_col (9b) << 17.  LDS ~24KB -> 6 blocks/CU.

__global__ void partA(const int* __restrict__ row, const int* __restrict__ col,
                      int* __restrict__ gcur, unsigned* __restrict__ tmp, int E) {
    __shared__ int histo[NBUCK];
    __shared__ int hbase[NBUCK];
    __shared__ int hscan[NBUCK];
    __shared__ int scanT[256];
    __shared__ unsigned staged[CHUNK];        // 16 KB
    __shared__ unsigned char sbk[CHUNK];      // 4 KB: bucket id per staged slot
    int tid = threadIdx.x;
    int start = blockIdx.x * CHUNK;
    for (int i = tid; i < NBUCK; i += 256) histo[i] = 0;
    __syncthreads();
    unsigned pk[16]; unsigned short lp[16]; unsigned char bk[16];
    for (int k = 0; k < 16; ++k) {
        int e = start + k * 256 + tid;
        bk[k] = 0xFF;
        if (e < E) {
            int cc = col[e];
            int b = cc >> BSHIFT;                          // 0..195
            pk[k] = (unsigned)row[e] | ((unsigned)(cc & ((1 << BSHIFT) - 1)) << 17);
            bk[k] = (unsigned char)b;
            lp[k] = (unsigned short)atomicAdd(&histo[b], 1);
        }
    }
    __syncthreads();
    int v = (tid < NBUCK) ? histo[tid] : 0;
    scanT[tid] = v;
    __syncthreads();
    for (int off = 1; off < 256; off <<= 1) {
        int t2 = (tid >= off) ? scanT[tid - off] : 0;
        __syncthreads();
        scanT[tid] += t2;
        __syncthreads();
    }
    if (tid < NBUCK) {
        hscan[tid] = scanT[tid] - v;                       // chunk-local exclusive
        if (v > 0) hbase[tid] = atomicAdd(&gcur[tid], v);  // reserve global run
    }
    __syncthreads();
    for (int k = 0; k < 16; ++k) {
        if (bk[k] != 0xFF) {
            int slot = hscan[bk[k]] + lp[k];
            staged[slot] = pk[k];
            sbk[slot] = bk[k];
        }
    }
    __syncthreads();
    int tot = scanT[255];
    for (int k = tid; k < tot; k += 256) {
        int b = sbk[k];
        tmp[hbase[b] + (k - hscan[b])] = staged[k];        // bucket-contiguous runs
    }
}

// ---------------- per-bucket degree histogram -> dinv ----------------

__global__ __launch_bounds__(1024) void degree_dinv(const int* __restrict__ bbase,
                                                    const unsigned* __restrict__ tmp,
                                                    float* __restrict__ dinv, int N) {
    __shared__ int hist[1 << BSHIFT];
    int b = blockIdx.x;
    int tid = threadIdx.x;
    if (tid < (1 << BSHIFT)) hist[tid] = 0;
    __syncthreads();
    int s = bbase[b], e = bbase[b + 1];
    for (int i = s + tid; i < e; i += 1024)
        atomicAdd(&hist[tmp[i] >> 17], 1);                 // LDS atomic
    __syncthreads();
    int node0 = b << BSHIFT;
    if (tid < (1 << BSHIFT) && node0 + tid < N)
        dinv[node0 + tid] = 1.0f / sqrtf((float)(hist[tid] + 1));   // +1 self-loop
}

// ---------------- layer 1 GEMM: hs = (x @ W1) * dinv  (stride-16, f=15 zeroed) ----

__global__ void gemm1_kernel(const float* __restrict__ x, const float* __restrict__ W,
                             const float* __restrict__ dinv, float* __restrict__ hs) {
    __shared__ float Wl[DD * HH];
    __shared__ float xs[16 * DD];
    int tid = threadIdx.x;
    for (int i = tid; i < DD * HH; i += 256) Wl[i] = W[i];
    size_t base = (size_t)blockIdx.x * 16 * DD;
    const float4* xv = (const float4*)(x + base);
    float4* xsv = (float4*)xs;
    xsv[tid]       = xv[tid];
    xsv[tid + 256] = xv[tid + 256];
    __syncthreads();
    int g = tid >> 4, f = tid & 15;
    int n = blockIdx.x * 16 + g;
    float val = 0.f;
    if (f < HH) {
        const float* xrow = xs + g * DD;
        float acc = 0.f;
#pragma unroll 8
        for (int k = 0; k < DD; ++k) acc += xrow[k] * Wl[k * HH + f];
        val = acc * dinv[n];
    }
    hs[((size_t)n << 4) + f] = val;
}

// ---------------- mid layers: in = relu(agg + b), hs' = (in @ W) * dinv ----------

__global__ void gemm_mid_kernel(const float* __restrict__ agg_in, const float* __restrict__ bias,
                                const float* __restrict__ W, const float* __restrict__ dinv,
                                float* __restrict__ hs) {
    __shared__ float Wl[HH * HH];
    __shared__ float s_in[256];          // 16 nodes x stride 16
    int tid = threadIdx.x;
    if (tid < HH * HH) Wl[tid] = W[tid];
    int n0 = blockIdx.x * 16;
    int g = tid >> 4, f = tid & 15;
    int n = n0 + g;
    if (f < HH) {
        float v = agg_in[((size_t)n << 4) + f] + bias[f];
        s_in[tid] = v > 0.f ? v : 0.f;
    }
    __syncthreads();
    float val = 0.f;
    if (f < HH) {
        const float* in = s_in + g * 16;
        float acc = 0.f;
#pragma unroll
        for (int k = 0; k < HH; ++k) acc += in[k] * Wl[k * HH + f];
        val = acc * dinv[n];
    }
    hs[((size_t)n << 4) + f] = val;
}

// ---------------- bucket aggregation: agg[c] = dinv[c]*(hs[c] + sum hs[row]) -----
// One block per (bucket, feature-half). LDS tile 512x8 floats, LDS float atomics.
// No csr_row, no rowptr, no shuffle reductions.

__global__ __launch_bounds__(1024) void bucket_agg(const int* __restrict__ bbase,
                                                   const unsigned* __restrict__ tmp,
                                                   const float* __restrict__ hs,
                                                   const float* __restrict__ dinv,
                                                   float* __restrict__ agg, int N) {
    __shared__ float acc[(1 << BSHIFT) * 8];   // 16 KB
    int b = blockIdx.x >> 1;
    int sub8 = (blockIdx.x & 1) * 8;
    int tid = threadIdx.x;
    for (int i = tid; i < (1 << BSHIFT) * 8; i += 1024) acc[i] = 0.f;
    __syncthreads();
    int s = bbase[b], e2 = bbase[b + 1];
    int f = tid & 7, eg = tid >> 3;            // 128 edges per block-iteration
#pragma unroll 4
    for (int e = s + eg; e < e2; e += 128) {
        unsigned v = tmp[e];
        float val = hs[((size_t)(v & 0x1FFFFu) << 4) + sub8 + f];
        atomicAdd(&acc[((v >> 17) << 3) + f], val);        // LDS float atomic
    }
    __syncthreads();
    int node0 = b << BSHIFT;
    int nn = min(1 << BSHIFT, N - node0);
    for (int i = tid; i < nn * 8; i += 1024) {
        int ln = i >> 3, ff = i & 7;
        int n = node0 + ln;
        size_t gi = ((size_t)n << 4) + sub8 + ff;
        agg[gi] = dinv[n] * (acc[i] + hs[gi]);             // self-loop folded in
    }
}

// ---------------- output GEMM: out = relu(agg + b3) @ Wc + bc ----------------

__global__ void gemm_out_kernel(const float* __restrict__ agg_in, const float* __restrict__ bias,
                                const float* __restrict__ Wc, const float* __restrict__ bc,
                                float* __restrict__ out) {
    __shared__ float Wl[HH * DD];
    __shared__ float s_in[32];
    int tid = threadIdx.x;
    for (int i = tid; i < HH * DD; i += 256) Wl[i] = Wc[i];
    int n0 = blockIdx.x * 2;
    if (tid < 32) {
        int gg = tid >> 4, ff = tid & 15;
        float v = (ff < HH) ? agg_in[((size_t)(n0 + gg) << 4) + ff] + bias[ff] : 0.f;
        s_in[tid] = v > 0.f ? v : 0.f;
    }
    __syncthreads();
    int g = tid >> 7, f = tid & 127;
    int n = n0 + g;
    const float* in = s_in + g * 16;
    float acc = bc[f];
#pragma unroll
    for (int k = 0; k < HH; ++k) acc += in[k] * Wl[k * DD + f];
    out[(size_t)n * DD + f] = acc;
}

// ---------------- launch ----------------

extern "C" void kernel_launch(void* const* d_in, const int* in_sizes, int n_in,
                              void* d_out, int out_size, void* d_ws, size_t ws_size,
                              hipStream_t stream) {
    const float* x  = (const float*)d_in[0];
    const int*   ei = (const int*)d_in[1];
    const float* W1 = (const float*)d_in[2];
    const float* b1 = (const float*)d_in[3];
    const float* W2 = (const float*)d_in[4];
    const float* b2 = (const float*)d_in[5];
    const float* W3 = (const float*)d_in[6];
    const float* b3 = (const float*)d_in[7];
    const float* Wc = (const float*)d_in[8];
    const float* bc = (const float*)d_in[9];
    float* out = (float*)d_out;

    int N = in_sizes[0] / DD;   // 100000
    int E = in_sizes[1] / 2;    // 6400000
    const int* row = ei;        // edge_index[0] = source
    const int* col = ei + E;    // edge_index[1] = target (aggregation index)

    char* ws = (char*)d_ws;
    size_t off = 0;
    auto alloc = [&](size_t bytes) {
        void* p = ws + off;
        off += (bytes + 255) & ~(size_t)255;
        return p;
    };
    float*    dinv   = (float*)   alloc((size_t)N * 4);
    int*      bcount = (int*)     alloc((size_t)NBUCK * 4);
    int*      bbase  = (int*)     alloc((size_t)(NBUCK + 1) * 4);
    int*      gcur   = (int*)     alloc((size_t)NBUCK * 4);
    unsigned* tmp    = (unsigned*)alloc((size_t)E * 4);          // 25.6 MB
    float*    hsBuf  = (float*)   alloc((size_t)N * 16 * 4);     // 6.4 MB
    float*    aggBuf = (float*)   alloc((size_t)N * 16 * 4);     // 6.4 MB
    (void)ws_size; (void)n_in; (void)out_size;                   // total ~39 MB

    int eblocks = (E + CHUNK - 1) / CHUNK;             // 1563

    // bucket counts + bases + partA cursors
    hipMemsetAsync(bcount, 0, (size_t)NBUCK * 4, stream);
    bucket_count<<<eblocks, 256, 0, stream>>>(col, bcount, E);
    scan196<<<1, 256, 0, stream>>>(bcount, bbase, gcur, E);

    // bin edges into bucket-grouped tmp; derive per-node dinv
    partA<<<eblocks, 256, 0, stream>>>(row, col, gcur, tmp, E);
    degree_dinv<<<NBUCK, 1024, 0, stream>>>(bbase, tmp, dinv, N);

    int nb16 = (N + 15) / 16;                          // 6250
    int agg_blocks = NBUCK * 2;                        // (bucket, feature-half)

    // layer 1
    gemm1_kernel<<<nb16, 256, 0, stream>>>(x, W1, dinv, hsBuf);
    bucket_agg<<<agg_blocks, 1024, 0, stream>>>(bbase, tmp, hsBuf, dinv, aggBuf, N);
    // layer 2
    gemm_mid_kernel<<<nb16, 256, 0, stream>>>(aggBuf, b1, W2, dinv, hsBuf);
    bucket_agg<<<agg_blocks, 1024, 0, stream>>>(bbase, tmp, hsBuf, dinv, aggBuf, N);
    // layer 3
    gemm_mid_kernel<<<nb16, 256, 0, stream>>>(aggBuf, b2, W3, dinv, hsBuf);
    bucket_agg<<<agg_blocks, 1024, 0, stream>>>(bbase, tmp, hsBuf, dinv, aggBuf, N);
    // output
    gemm_out_kernel<<<(N + 1) / 2, 256, 0, stream>>>(aggBuf, b3, Wc, bc, out);
}